// Round 5
// baseline (285.707 us; speedup 1.0000x reference)
//
#include <hip/hip_runtime.h>

#define NC 91
#define NBIN 182          // bins 0..90 = union counts, 91..181 = intersection counts
#define NROWS 46          // ceil(NBIN/4) dword-rows of 256 thread-columns
#define NB 32
#define HW (1024 * 1024)
#define NT 256
#define PPT 64            // per-thread per-bin count <= 128 < 255, u8 safe
#define PIX_PER_BLOCK (NT * PPT)   // 16384

// dword(bin, tid) = (bin>>2)*256 + tid : each dword holds 4 byte-counters
// (bins 4r..4r+3) PRIVATE to thread tid. bank = tid%32 -> fixed 2-way (free).

__global__ __launch_bounds__(256) void hist_kernel(const int* __restrict__ x,
                                                   const int* __restrict__ t,
                                                   int* __restrict__ g_hist) {
    __shared__ unsigned int s_h[NROWS * 256];      // 47,104 B
    __shared__ unsigned int s_part[NROWS][4][2];   // flush partials, 1,472 B

    const int tid = threadIdx.x;

    for (int i = tid; i < NROWS * 256; i += NT) s_h[i] = 0u;
    __syncthreads();

    const int b = blockIdx.y;
    const long base = (long)b * HW + (long)blockIdx.x * PIX_PER_BLOCK;
    const int4* __restrict__ x4 = (const int4*)(x + base) + tid;
    const int4* __restrict__ t4 = (const int4*)(t + base) + tid;

#pragma unroll 4
    for (int i = 0; i < PPT / 4; ++i) {
        int4 xv = x4[i * NT];
        int4 tv = t4[i * NT];
        // per pixel: union[x]++, then inter[x]++ if match else union[t]++
        // dword-wide RMW, reads batched before writes, same-dword merged.
#define PIX(X, T) { \
            int u = (X); \
            int v = ((X) == (T)) ? (NC + (X)) : (T); \
            int au = ((u >> 2) << 8) + tid; \
            int av = ((v >> 2) << 8) + tid; \
            unsigned mu = 1u << ((u & 3) << 3); \
            unsigned mv = 1u << ((v & 3) << 3); \
            unsigned ru = s_h[au]; \
            unsigned rv = s_h[av]; \
            bool same = (au == av); \
            unsigned wu = ru + mu + (same ? mv : 0u); \
            unsigned wv = same ? wu : (rv + mv); \
            s_h[au] = wu; \
            s_h[av] = wv; \
        }
        PIX(xv.x, tv.x)
        PIX(xv.y, tv.y)
        PIX(xv.z, tv.z)
        PIX(xv.w, tv.w)
#undef PIX
    }
    __syncthreads();

    // flush phase A: thread (row,q) sums 64 thread-columns of its row into
    // packed u16x2 partials (slo: bins 4r,4r+2; shi: 4r+1,4r+3).
    // addr swizzle (k+tid)&63 -> bank (k+tid)%32 -> 2-way only.
    if (tid < NROWS * 4) {
        const int row = tid >> 2, q = tid & 3;
        const unsigned int* rp = s_h + row * 256 + q * 64;
        unsigned slo = 0, shi = 0;
#pragma unroll 8
        for (int k = 0; k < 64; ++k) {
            unsigned d = rp[(k + tid) & 63];
            slo += d & 0x00FF00FFu;
            shi += (d >> 8) & 0x00FF00FFu;
        }
        s_part[row][q][0] = slo;
        s_part[row][q][1] = shi;
    }
    __syncthreads();

    // flush phase B: bin c = 4r+k -> sel = k&1 (slo/shi), half = k>>1 (u16 lane)
    for (int c = tid; c < NBIN; c += NT) {
        const int row = c >> 2, k = c & 3;
        const int sel = k & 1, half = k >> 1;
        unsigned s = 0;
#pragma unroll
        for (int q = 0; q < 4; ++q)
            s += (s_part[row][q][sel] >> (16 * half)) & 0xFFFFu;
        atomicAdd(&g_hist[b * NBIN + c], (int)s);
    }
}

__global__ __launch_bounds__(64) void finalize_kernel(const int* __restrict__ g_hist,
                                                      const float* __restrict__ smooth,
                                                      float* __restrict__ out) {
    const int b = blockIdx.x;
    const int lane = threadIdx.x;  // 0..63
    const float s = smooth[0];
    float acc = 0.0f;
    for (int c = lane; c < NC; c += 64) {
        float un = (float)g_hist[b * NBIN + c];
        float in = (float)g_hist[b * NBIN + NC + c];
        acc += (in + s) / (un + s);
    }
#pragma unroll
    for (int off = 32; off > 0; off >>= 1)
        acc += __shfl_down(acc, off, 64);
    if (lane == 0) out[b] = acc / (float)NC;
}

extern "C" void kernel_launch(void* const* d_in, const int* in_sizes, int n_in,
                              void* d_out, int out_size, void* d_ws, size_t ws_size,
                              hipStream_t stream) {
    const int* x = (const int*)d_in[0];
    const int* t = (const int*)d_in[1];
    const float* smooth = (const float*)d_in[2];
    float* out = (float*)d_out;

    int* g_hist = (int*)d_ws;

    hipMemsetAsync(d_ws, 0, NB * NBIN * sizeof(int), stream);

    dim3 grid(HW / PIX_PER_BLOCK, NB);  // 64 x 32 = 2048 blocks
    hist_kernel<<<grid, NT, 0, stream>>>(x, t, g_hist);
    finalize_kernel<<<NB, 64, 0, stream>>>(g_hist, smooth, out);
}